// Round 1
// baseline (586.543 us; speedup 1.0000x reference)
//
#include <hip/hip_runtime.h>
#include <stdint.h>

#define SEQ_ 2048
#define DIM_ 1024
#define HD_ 64
#define NH_ 16

typedef __bf16 bf16x8 __attribute__((ext_vector_type(8)));
typedef float f32x4 __attribute__((ext_vector_type(4)));
typedef __attribute__((address_space(1))) unsigned int as1_uint;
typedef __attribute__((address_space(3))) unsigned int as3_uint;

__device__ __forceinline__ unsigned short f2bf(float f) {
  unsigned u = __builtin_bit_cast(unsigned, f);
  u += 0x7fffu + ((u >> 16) & 1u);
  return (unsigned short)(u >> 16);
}

// async global->LDS, 16B per lane. LDS dest is wave-uniform base + lane*16.
__device__ __forceinline__ void gload_lds16(const void* g, void* l) {
  __builtin_amdgcn_global_load_lds(
      reinterpret_cast<as1_uint*>(reinterpret_cast<uintptr_t>(g)),
      reinterpret_cast<as3_uint*>(
          static_cast<unsigned int>(reinterpret_cast<uintptr_t>(l))),
      16, 0, 0);
}

// ---------------- weight transpose + fp32->bf16 convert: Wt[n][k] = W[k][n]
__global__ __launch_bounds__(256) void transpose_cvt(
    const float* __restrict__ W, unsigned short* __restrict__ Wt, int K, int N) {
  __shared__ float t[32][33];
  const int tx = threadIdx.x & 31, ty = threadIdx.x >> 5;  // ty 0..7
  const int n0 = blockIdx.x * 32, k0 = blockIdx.y * 32;
#pragma unroll
  for (int i = 0; i < 4; i++)
    t[ty + i * 8][tx] = W[(size_t)(k0 + ty + i * 8) * N + n0 + tx];
  __syncthreads();
#pragma unroll
  for (int i = 0; i < 4; i++)
    Wt[(size_t)(n0 + ty + i * 8) * K + k0 + tx] = f2bf(t[tx][ty + i * 8]);
}

// ---------------- rmsnorm over DIM: out = x/max(||x||,eps)*32*g  (bf16)
__global__ __launch_bounds__(256) void rmsnorm_k(
    const float* __restrict__ x, const float* __restrict__ g,
    unsigned short* __restrict__ out) {
  const int row = blockIdx.x;
  const float4* xr = (const float4*)(x + (size_t)row * DIM_);
  float4 v = xr[threadIdx.x];
  float ss = v.x * v.x + v.y * v.y + v.z * v.z + v.w * v.w;
  ss += __shfl_xor(ss, 1);  ss += __shfl_xor(ss, 2);  ss += __shfl_xor(ss, 4);
  ss += __shfl_xor(ss, 8);  ss += __shfl_xor(ss, 16); ss += __shfl_xor(ss, 32);
  __shared__ float red[4];
  if ((threadIdx.x & 63) == 0) red[threadIdx.x >> 6] = ss;
  __syncthreads();
  float tot = red[0] + red[1] + red[2] + red[3];
  float sc = 32.0f * g[0] / fmaxf(sqrtf(tot), 1e-12f);
  unsigned short* orow = out + (size_t)row * DIM_;
  const int b4 = threadIdx.x * 4;
  orow[b4 + 0] = f2bf(v.x * sc);
  orow[b4 + 1] = f2bf(v.y * sc);
  orow[b4 + 2] = f2bf(v.z * sc);
  orow[b4 + 3] = f2bf(v.w * sc);
}

// ---------------- GEMM: C[M,N] = A[M,K](bf16) @ Bt[N,K](bf16)^T + bias (+res)(+gelu)
// EPI: 0 = bias, f32 out; 1 = bias + residual, f32 out; 2 = bias + gelu, bf16 out
template <int EPI>
__global__ __launch_bounds__(256, 2) void gemm_bf16(
    const unsigned short* __restrict__ A, const unsigned short* __restrict__ Bt,
    const float* __restrict__ bias, const float* __restrict__ res,
    void* __restrict__ Cout, int M, int N, int K) {
  __shared__ __align__(16) unsigned short As[128 * 32];
  __shared__ __align__(16) unsigned short Bs[128 * 32];
  const int tid = threadIdx.x;
  const int w = tid >> 6, lane = tid & 63;
  const int wm = w >> 1, wn = w & 1;
  const int quad = lane >> 4, l15 = lane & 15;
  const int bn = blockIdx.x, bm = blockIdx.y;

  f32x4 acc[4][4];
#pragma unroll
  for (int i = 0; i < 4; i++)
#pragma unroll
    for (int j = 0; j < 4; j++) acc[i][j] = f32x4{0.f, 0.f, 0.f, 0.f};

  // staging: 512 chunks of 16B per tile; wave w handles chunks w*64+lane, +256
  const int r0 = w * 16 + (lane >> 2);
  const int c0 = (lane & 3) * 8;
  const unsigned short* gA0 = A + (size_t)(bm * 128 + r0) * K + c0;
  const unsigned short* gA1 = gA0 + (size_t)64 * K;
  const unsigned short* gB0 = Bt + (size_t)(bn * 128 + r0) * K + c0;
  const unsigned short* gB1 = gB0 + (size_t)64 * K;
  unsigned short* lA0 = As + w * 512;
  unsigned short* lA1 = As + 2048 + w * 512;
  unsigned short* lB0 = Bs + w * 512;
  unsigned short* lB1 = Bs + 2048 + w * 512;

  for (int kk = 0; kk < K; kk += 32) {
    gload_lds16(gA0, lA0);
    gload_lds16(gA1, lA1);
    gload_lds16(gB0, lB0);
    gload_lds16(gB1, lB1);
    gA0 += 32; gA1 += 32; gB0 += 32; gB1 += 32;
    __syncthreads();  // drains vmcnt(0): LDS tiles complete
    bf16x8 af[4], bf[4];
#pragma unroll
    for (int i = 0; i < 4; i++) {
      af[i] = *(const bf16x8*)&As[(wm * 64 + i * 16 + l15) * 32 + quad * 8];
      bf[i] = *(const bf16x8*)&Bs[(wn * 64 + i * 16 + l15) * 32 + quad * 8];
    }
#pragma unroll
    for (int i = 0; i < 4; i++)
#pragma unroll
      for (int j = 0; j < 4; j++)
        acc[i][j] = __builtin_amdgcn_mfma_f32_16x16x32_bf16(af[i], bf[j], acc[i][j], 0, 0, 0);
    __syncthreads();  // protect LDS before next stage
  }

  const int rowb = bm * 128 + wm * 64;
  const int colb = bn * 128 + wn * 64;
#pragma unroll
  for (int i = 0; i < 4; i++) {
#pragma unroll
    for (int j = 0; j < 4; j++) {
      const int col = colb + j * 16 + l15;
      const float bv = bias[col];
#pragma unroll
      for (int r = 0; r < 4; r++) {
        const int row = rowb + i * 16 + quad * 4 + r;  // C/D: row=quad*4+reg, col=lane&15
        const size_t idx = (size_t)row * N + col;
        float v = acc[i][j][r] + bv;
        if (EPI == 0) {
          ((float*)Cout)[idx] = v;
        } else if (EPI == 1) {
          ((float*)Cout)[idx] = v + res[idx];
        } else {
          float t = tanhf(0.7978845608028654f * (v + 0.044715f * v * v * v));
          ((unsigned short*)Cout)[idx] = f2bf(0.5f * v * (1.0f + t));
        }
      }
    }
  }
}

// ---------------- qkv postprocess: per-head L2 norm of q,k; v transposed
// Qs[bh][n][d] = qhat*g_q   (score scale 1/8 folded in: 8*g*1/8 = g)
// Ks[bh][n][d] = khat*8*g_k ;  VT[bh][d][n] = v
__global__ __launch_bounds__(256) void qkv_post(
    const float* __restrict__ qkv, const float* __restrict__ gq,
    const float* __restrict__ gk, unsigned short* __restrict__ Qs,
    unsigned short* __restrict__ Ks, unsigned short* __restrict__ VT) {
  const int item = blockIdx.x * 4 + (threadIdx.x >> 6);  // 0..65535
  const int lane = threadIdx.x & 63;
  const int h = item & 15;
  const int rn = item >> 4;  // b*SEQ+n
  const int b = rn >> 11, n = rn & 2047;
  const float* base = qkv + (size_t)rn * 3072 + h * 64;
  const float qv = base[lane];
  const float kv = base[1024 + lane];
  const float vv = base[2048 + lane];
  float sq = qv * qv, sk = kv * kv;
  sq += __shfl_xor(sq, 1);  sk += __shfl_xor(sk, 1);
  sq += __shfl_xor(sq, 2);  sk += __shfl_xor(sk, 2);
  sq += __shfl_xor(sq, 4);  sk += __shfl_xor(sk, 4);
  sq += __shfl_xor(sq, 8);  sk += __shfl_xor(sk, 8);
  sq += __shfl_xor(sq, 16); sk += __shfl_xor(sk, 16);
  sq += __shfl_xor(sq, 32); sk += __shfl_xor(sk, 32);
  const float qs = qv / fmaxf(sqrtf(sq), 1e-12f) * gq[0];
  const float ks = kv / fmaxf(sqrtf(sk), 1e-12f) * (8.0f * gk[0]);
  const int bh = b * 16 + h;
  Qs[((size_t)bh * SEQ_ + n) * HD_ + lane] = f2bf(qs);
  Ks[((size_t)bh * SEQ_ + n) * HD_ + lane] = f2bf(ks);
  VT[((size_t)bh * HD_ + lane) * SEQ_ + n] = f2bf(vv);
}

// ---------------- flash attention: grid (bh=32, qtile=32), 4 waves x 16 q-rows
__global__ __launch_bounds__(256) void attn_fwd(
    const unsigned short* __restrict__ Qs, const unsigned short* __restrict__ Ks,
    const unsigned short* __restrict__ VT, unsigned short* __restrict__ O) {
  __shared__ __align__(16) unsigned short P[4 * 512];  // per-wave 16x32 bf16
  const int bh = blockIdx.x, qt = blockIdx.y;
  const int w = threadIdx.x >> 6, lane = threadIdx.x & 63;
  const int quad = lane >> 4, l15 = lane & 15;
  const unsigned short* Qb = Qs + (size_t)bh * SEQ_ * HD_;
  const unsigned short* Kb = Ks + (size_t)bh * SEQ_ * HD_;
  const unsigned short* Vb = VT + (size_t)bh * HD_ * SEQ_;
  const int q0 = qt * 64 + w * 16;
  const bf16x8 qa0 = *(const bf16x8*)&Qb[(q0 + l15) * HD_ + quad * 8];
  const bf16x8 qa1 = *(const bf16x8*)&Qb[(q0 + l15) * HD_ + 32 + quad * 8];
  f32x4 o[4];
  float mrow[4], lrow[4];
#pragma unroll
  for (int c = 0; c < 4; c++) o[c] = f32x4{0.f, 0.f, 0.f, 0.f};
#pragma unroll
  for (int r = 0; r < 4; r++) { mrow[r] = -3.0e38f; lrow[r] = 0.0f; }
  unsigned short* Pw = P + w * 512;

  for (int kt = 0; kt < SEQ_ / 32; kt++) {
    const int n0 = kt * 32;
    const bf16x8 k0a = *(const bf16x8*)&Kb[(n0 + l15) * HD_ + quad * 8];
    const bf16x8 k0b = *(const bf16x8*)&Kb[(n0 + l15) * HD_ + 32 + quad * 8];
    const bf16x8 k1a = *(const bf16x8*)&Kb[(n0 + 16 + l15) * HD_ + quad * 8];
    const bf16x8 k1b = *(const bf16x8*)&Kb[(n0 + 16 + l15) * HD_ + 32 + quad * 8];
    f32x4 s0 = f32x4{0.f, 0.f, 0.f, 0.f}, s1 = f32x4{0.f, 0.f, 0.f, 0.f};
    s0 = __builtin_amdgcn_mfma_f32_16x16x32_bf16(qa0, k0a, s0, 0, 0, 0);
    s0 = __builtin_amdgcn_mfma_f32_16x16x32_bf16(qa1, k0b, s0, 0, 0, 0);
    s1 = __builtin_amdgcn_mfma_f32_16x16x32_bf16(qa0, k1a, s1, 0, 0, 0);
    s1 = __builtin_amdgcn_mfma_f32_16x16x32_bf16(qa1, k1b, s1, 0, 0, 0);
#pragma unroll
    for (int r = 0; r < 4; r++) {
      float mt = fmaxf(s0[r], s1[r]);
      mt = fmaxf(mt, __shfl_xor(mt, 1));
      mt = fmaxf(mt, __shfl_xor(mt, 2));
      mt = fmaxf(mt, __shfl_xor(mt, 4));
      mt = fmaxf(mt, __shfl_xor(mt, 8));
      const float mn = fmaxf(mrow[r], mt);
      const float al = __expf(mrow[r] - mn);
      const float p0 = __expf(s0[r] - mn);
      const float p1 = __expf(s1[r] - mn);
      float rs = p0 + p1;
      rs += __shfl_xor(rs, 1);
      rs += __shfl_xor(rs, 2);
      rs += __shfl_xor(rs, 4);
      rs += __shfl_xor(rs, 8);
      lrow[r] = lrow[r] * al + rs;
      mrow[r] = mn;
      Pw[(quad * 4 + r) * 32 + l15] = f2bf(p0);        // C-layout -> LDS
      Pw[(quad * 4 + r) * 32 + 16 + l15] = f2bf(p1);
      o[0][r] *= al; o[1][r] *= al; o[2][r] *= al; o[3][r] *= al;
    }
    asm volatile("s_waitcnt lgkmcnt(0)" ::: "memory");
    const bf16x8 pa = *(const bf16x8*)&Pw[l15 * 32 + quad * 8];  // A-layout read
#pragma unroll
    for (int c = 0; c < 4; c++) {
      const bf16x8 vb = *(const bf16x8*)&Vb[(size_t)(c * 16 + l15) * SEQ_ + n0 + quad * 8];
      o[c] = __builtin_amdgcn_mfma_f32_16x16x32_bf16(pa, vb, o[c], 0, 0, 0);
    }
  }
  const int b = bh >> 4, h = bh & 15;
#pragma unroll
  for (int c = 0; c < 4; c++) {
#pragma unroll
    for (int r = 0; r < 4; r++) {
      const float ov = o[c][r] / lrow[r];
      const int row = q0 + quad * 4 + r;
      O[((size_t)(b * SEQ_ + row)) * DIM_ + h * 64 + c * 16 + l15] = f2bf(ov);
    }
  }
}

extern "C" void kernel_launch(void* const* d_in, const int* in_sizes, int n_in,
                              void* d_out, int out_size, void* d_ws, size_t ws_size,
                              hipStream_t stream) {
  const float* x      = (const float*)d_in[0];
  const float* w_qkv  = (const float*)d_in[1];
  const float* b_qkv  = (const float*)d_in[2];
  const float* w_proj = (const float*)d_in[3];
  const float* b_proj = (const float*)d_in[4];
  const float* g1     = (const float*)d_in[5];
  const float* g2     = (const float*)d_in[6];
  const float* gq     = (const float*)d_in[7];
  const float* gk     = (const float*)d_in[8];
  const float* w_fc1  = (const float*)d_in[9];
  const float* b_fc1  = (const float*)d_in[10];
  const float* w_fc2  = (const float*)d_in[11];
  const float* b_fc2  = (const float*)d_in[12];
  float* out = (float*)d_out;

  char* p = (char*)d_ws;
  auto alloc = [&](size_t bytes) {
    char* r = p;
    p += (bytes + 255) & ~(size_t)255;
    return r;
  };
  unsigned short* wqkvT  = (unsigned short*)alloc(3072ull * 1024 * 2);
  unsigned short* wprojT = (unsigned short*)alloc(1024ull * 1024 * 2);
  unsigned short* wfc1T  = (unsigned short*)alloc(4096ull * 1024 * 2);
  unsigned short* wfc2T  = (unsigned short*)alloc(1024ull * 4096 * 2);
  unsigned short* h1     = (unsigned short*)alloc(4096ull * 1024 * 2);  // also Obuf
  char* big = alloc(4096ull * 3072 * 4);  // qkv f32; later reused as h3 bf16
  float* qkvf = (float*)big;
  unsigned short* h3 = (unsigned short*)big;
  unsigned short* QsB = (unsigned short*)alloc(32ull * SEQ_ * HD_ * 2);
  unsigned short* KsB = (unsigned short*)alloc(32ull * SEQ_ * HD_ * 2);
  unsigned short* VTB = (unsigned short*)alloc(32ull * SEQ_ * HD_ * 2);
  float* x2 = (float*)alloc(4096ull * 1024 * 4);
  unsigned short* h2 = (unsigned short*)alloc(4096ull * 1024 * 2);
  unsigned short* Obuf = h1;  // h1 dead after qkv GEMM

  // 1. weight transpose+convert (Wt[n][k])
  transpose_cvt<<<dim3(3072 / 32, 1024 / 32), 256, 0, stream>>>(w_qkv, wqkvT, 1024, 3072);
  transpose_cvt<<<dim3(1024 / 32, 1024 / 32), 256, 0, stream>>>(w_proj, wprojT, 1024, 1024);
  transpose_cvt<<<dim3(4096 / 32, 1024 / 32), 256, 0, stream>>>(w_fc1, wfc1T, 1024, 4096);
  transpose_cvt<<<dim3(1024 / 32, 4096 / 32), 256, 0, stream>>>(w_fc2, wfc2T, 4096, 1024);
  // 2. rmsnorm1: x -> h1 (bf16)
  rmsnorm_k<<<4096, 256, 0, stream>>>(x, g1, h1);
  // 3. qkv = h1 @ w_qkv + b_qkv  (f32 out)
  gemm_bf16<0><<<dim3(3072 / 128, 4096 / 128), 256, 0, stream>>>(
      h1, wqkvT, b_qkv, nullptr, qkvf, 4096, 3072, 1024);
  // 4. per-head q/k norm + v transpose
  qkv_post<<<16384, 256, 0, stream>>>(qkvf, gq, gk, QsB, KsB, VTB);
  // 5. attention -> Obuf bf16 [B,N,H*d]
  attn_fwd<<<dim3(32, 32), 256, 0, stream>>>(QsB, KsB, VTB, Obuf);
  // 6. x2 = x + Obuf @ w_proj + b_proj  (f32)
  gemm_bf16<1><<<dim3(1024 / 128, 4096 / 128), 256, 0, stream>>>(
      Obuf, wprojT, b_proj, x, x2, 4096, 1024, 1024);
  // 7. rmsnorm2: x2 -> h2
  rmsnorm_k<<<4096, 256, 0, stream>>>(x2, g2, h2);
  // 8. h3 = gelu(h2 @ w_fc1 + b_fc1)  (bf16)
  gemm_bf16<2><<<dim3(4096 / 128, 4096 / 128), 256, 0, stream>>>(
      h2, wfc1T, b_fc1, nullptr, h3, 4096, 4096, 1024);
  // 9. out = x2 + h3 @ w_fc2 + b_fc2  (f32)
  gemm_bf16<1><<<dim3(1024 / 128, 4096 / 128), 256, 0, stream>>>(
      h3, wfc2T, b_fc2, x2, out, 4096, 1024, 4096);
}

// Round 3
// 428.690 us; speedup vs baseline: 1.3682x; 1.3682x over previous
//
#include <hip/hip_runtime.h>
#include <stdint.h>

#define SEQ_ 2048
#define DIM_ 1024
#define HD_ 64
#define NH_ 16

typedef __bf16 bf16x8 __attribute__((ext_vector_type(8)));
typedef float f32x4 __attribute__((ext_vector_type(4)));
typedef __attribute__((address_space(1))) unsigned int as1_uint;
typedef __attribute__((address_space(3))) unsigned int as3_uint;

__device__ __forceinline__ unsigned short f2bf(float f) {
  unsigned u = __builtin_bit_cast(unsigned, f);
  u += 0x7fffu + ((u >> 16) & 1u);
  return (unsigned short)(u >> 16);
}

// async global->LDS, 16B per lane. LDS dest is wave-uniform base + lane*16.
__device__ __forceinline__ void gload_lds16(const void* g, void* l) {
  __builtin_amdgcn_global_load_lds(
      reinterpret_cast<as1_uint*>(reinterpret_cast<uintptr_t>(g)),
      reinterpret_cast<as3_uint*>(
          static_cast<unsigned int>(reinterpret_cast<uintptr_t>(l))),
      16, 0, 0);
}

// ---------------- weight transpose + fp32->bf16 convert: Wt[n][k] = W[k][n]
__global__ __launch_bounds__(256) void transpose_cvt(
    const float* __restrict__ W, unsigned short* __restrict__ Wt, int K, int N) {
  __shared__ float t[32][33];
  const int tx = threadIdx.x & 31, ty = threadIdx.x >> 5;  // ty 0..7
  const int n0 = blockIdx.x * 32, k0 = blockIdx.y * 32;
#pragma unroll
  for (int i = 0; i < 4; i++)
    t[ty + i * 8][tx] = W[(size_t)(k0 + ty + i * 8) * N + n0 + tx];
  __syncthreads();
#pragma unroll
  for (int i = 0; i < 4; i++)
    Wt[(size_t)(n0 + ty + i * 8) * K + k0 + tx] = f2bf(t[tx][ty + i * 8]);
}

// ---------------- rmsnorm over DIM: out = x/max(||x||,eps)*32*g  (bf16)
__global__ __launch_bounds__(256) void rmsnorm_k(
    const float* __restrict__ x, const float* __restrict__ g,
    unsigned short* __restrict__ out) {
  const int row = blockIdx.x;
  const float4* xr = (const float4*)(x + (size_t)row * DIM_);
  float4 v = xr[threadIdx.x];
  float ss = v.x * v.x + v.y * v.y + v.z * v.z + v.w * v.w;
  ss += __shfl_xor(ss, 1);  ss += __shfl_xor(ss, 2);  ss += __shfl_xor(ss, 4);
  ss += __shfl_xor(ss, 8);  ss += __shfl_xor(ss, 16); ss += __shfl_xor(ss, 32);
  __shared__ float red[4];
  if ((threadIdx.x & 63) == 0) red[threadIdx.x >> 6] = ss;
  __syncthreads();
  float tot = red[0] + red[1] + red[2] + red[3];
  float sc = 32.0f * g[0] / fmaxf(sqrtf(tot), 1e-12f);
  unsigned short* orow = out + (size_t)row * DIM_;
  const int b4 = threadIdx.x * 4;
  orow[b4 + 0] = f2bf(v.x * sc);
  orow[b4 + 1] = f2bf(v.y * sc);
  orow[b4 + 2] = f2bf(v.z * sc);
  orow[b4 + 3] = f2bf(v.w * sc);
}

// ---------------- GEMM: C[M,N] = A[M,K](bf16) @ Bt[N,K](bf16)^T + bias (+res)(+gelu)
// EPI: 0 = bias, f32 out; 1 = bias + residual, f32 out; 2 = bias + gelu, bf16 out
template <int EPI>
__global__ __launch_bounds__(256, 2) void gemm_bf16(
    const unsigned short* __restrict__ A, const unsigned short* __restrict__ Bt,
    const float* __restrict__ bias, const float* __restrict__ res,
    void* __restrict__ Cout, int M, int N, int K) {
  __shared__ __align__(16) unsigned short As[128 * 32];
  __shared__ __align__(16) unsigned short Bs[128 * 32];
  const int tid = threadIdx.x;
  const int w = tid >> 6, lane = tid & 63;
  const int wm = w >> 1, wn = w & 1;
  const int quad = lane >> 4, l15 = lane & 15;
  const int bn = blockIdx.x, bm = blockIdx.y;

  f32x4 acc[4][4];
#pragma unroll
  for (int i = 0; i < 4; i++)
#pragma unroll
    for (int j = 0; j < 4; j++) acc[i][j] = f32x4{0.f, 0.f, 0.f, 0.f};

  const int r0 = w * 16 + (lane >> 2);
  const int c0 = (lane & 3) * 8;
  const unsigned short* gA0 = A + (size_t)(bm * 128 + r0) * K + c0;
  const unsigned short* gA1 = gA0 + (size_t)64 * K;
  const unsigned short* gB0 = Bt + (size_t)(bn * 128 + r0) * K + c0;
  const unsigned short* gB1 = gB0 + (size_t)64 * K;
  unsigned short* lA0 = As + w * 512;
  unsigned short* lA1 = As + 2048 + w * 512;
  unsigned short* lB0 = Bs + w * 512;
  unsigned short* lB1 = Bs + 2048 + w * 512;

  for (int kk = 0; kk < K; kk += 32) {
    gload_lds16(gA0, lA0);
    gload_lds16(gA1, lA1);
    gload_lds16(gB0, lB0);
    gload_lds16(gB1, lB1);
    gA0 += 32; gA1 += 32; gB0 += 32; gB1 += 32;
    __syncthreads();
    bf16x8 af[4], bf[4];
#pragma unroll
    for (int i = 0; i < 4; i++) {
      af[i] = *(const bf16x8*)&As[(wm * 64 + i * 16 + l15) * 32 + quad * 8];
      bf[i] = *(const bf16x8*)&Bs[(wn * 64 + i * 16 + l15) * 32 + quad * 8];
    }
#pragma unroll
    for (int i = 0; i < 4; i++)
#pragma unroll
      for (int j = 0; j < 4; j++)
        acc[i][j] = __builtin_amdgcn_mfma_f32_16x16x32_bf16(af[i], bf[j], acc[i][j], 0, 0, 0);
    __syncthreads();
  }

  const int rowb = bm * 128 + wm * 64;
  const int colb = bn * 128 + wn * 64;
#pragma unroll
  for (int i = 0; i < 4; i++) {
#pragma unroll
    for (int j = 0; j < 4; j++) {
      const int col = colb + j * 16 + l15;
      const float bv = bias[col];
#pragma unroll
      for (int r = 0; r < 4; r++) {
        const int row = rowb + i * 16 + quad * 4 + r;
        const size_t idx = (size_t)row * N + col;
        float v = acc[i][j][r] + bv;
        if (EPI == 0) {
          ((float*)Cout)[idx] = v;
        } else if (EPI == 1) {
          ((float*)Cout)[idx] = v + res[idx];
        } else {
          float t = tanhf(0.7978845608028654f * (v + 0.044715f * v * v * v));
          ((unsigned short*)Cout)[idx] = f2bf(0.5f * v * (1.0f + t));
        }
      }
    }
  }
}

// ---------------- qkv postprocess: per-head L2 norm of q,k; v transposed
__global__ __launch_bounds__(256) void qkv_post(
    const float* __restrict__ qkv, const float* __restrict__ gq,
    const float* __restrict__ gk, unsigned short* __restrict__ Qs,
    unsigned short* __restrict__ Ks, unsigned short* __restrict__ VT) {
  const int item = blockIdx.x * 4 + (threadIdx.x >> 6);
  const int lane = threadIdx.x & 63;
  const int h = item & 15;
  const int rn = item >> 4;  // b*SEQ+n
  const int b = rn >> 11, n = rn & 2047;
  const float* base = qkv + (size_t)rn * 3072 + h * 64;
  const float qv = base[lane];
  const float kv = base[1024 + lane];
  const float vv = base[2048 + lane];
  float sq = qv * qv, sk = kv * kv;
  sq += __shfl_xor(sq, 1);  sk += __shfl_xor(sk, 1);
  sq += __shfl_xor(sq, 2);  sk += __shfl_xor(sk, 2);
  sq += __shfl_xor(sq, 4);  sk += __shfl_xor(sk, 4);
  sq += __shfl_xor(sq, 8);  sk += __shfl_xor(sk, 8);
  sq += __shfl_xor(sq, 16); sk += __shfl_xor(sk, 16);
  sq += __shfl_xor(sq, 32); sk += __shfl_xor(sk, 32);
  const float qs = qv / fmaxf(sqrtf(sq), 1e-12f) * gq[0];
  const float ks = kv / fmaxf(sqrtf(sk), 1e-12f) * (8.0f * gk[0]);
  const int bh = b * 16 + h;
  Qs[((size_t)bh * SEQ_ + n) * HD_ + lane] = f2bf(qs);
  Ks[((size_t)bh * SEQ_ + n) * HD_ + lane] = f2bf(ks);
  VT[((size_t)bh * HD_ + lane) * SEQ_ + n] = f2bf(vv);
}

// ---------------- flash attention, fixed-max softmax (scores bounded by 8|gq*gk|)
// grid (bh=32, qt=32); block = 4 waves x 16 q-rows; K-tile = 64 keys staged in LDS
#define PLD_ 72  // P row stride in shorts; must be >= 64 (16x64 tile)
__global__ __launch_bounds__(256) void attn_fwd(
    const unsigned short* __restrict__ Qs, const unsigned short* __restrict__ Ks,
    const unsigned short* __restrict__ VT, const float* __restrict__ gq,
    const float* __restrict__ gk, unsigned short* __restrict__ O) {
  __shared__ __align__(16) unsigned short Kl[2][64][32];  // [kc][key][d-chunk] 8KB
  __shared__ __align__(16) unsigned short Vl[2][64][32];  // [kc][d][key-chunk] 8KB
  __shared__ __align__(16) unsigned short Pl[4][16 * PLD_];  // per-wave 16x64, ld=72
  const int bh = blockIdx.x, qt = blockIdx.y;
  const int w = threadIdx.x >> 6, lane = threadIdx.x & 63;
  const int quad = lane >> 4, l15 = lane & 15;
  const float M = 8.0f * fabsf(gq[0] * gk[0]);
  const unsigned short* Qb = Qs + (size_t)bh * SEQ_ * HD_;
  const unsigned short* Kb = Ks + (size_t)bh * SEQ_ * HD_;
  const unsigned short* Vb = VT + (size_t)bh * HD_ * SEQ_;
  const int q0 = qt * 64 + w * 16;
  const bf16x8 qa0 = *(const bf16x8*)&Qb[(q0 + l15) * HD_ + quad * 8];
  const bf16x8 qa1 = *(const bf16x8*)&Qb[(q0 + l15) * HD_ + 32 + quad * 8];

  // DMA plan: 16 issues/block of 1KB, wave w does idx = w*4+i
  const unsigned short* gsrc[4];
  unsigned short* ldst[4];
  int gstep[4];
#pragma unroll
  for (int i = 0; i < 4; i++) {
    const int idx = w * 4 + i;
    if (idx < 8) {  // K: kc = idx>>2 (d-half), kh = idx&3 (16-key group)
      const int kc = idx >> 2, kh = idx & 3;
      ldst[i] = &Kl[kc][kh * 16][0];
      gsrc[i] = &Kb[(size_t)(kh * 16 + (lane >> 2)) * HD_ + kc * 32 + (lane & 3) * 8];
      gstep[i] = 64 * HD_;  // advance 64 keys
    } else {        // V: kc = key-half, dh = 16-d group
      const int j = idx - 8;
      const int kc = j >> 2, dh = j & 3;
      ldst[i] = &Vl[kc][dh * 16][0];
      gsrc[i] = &Vb[(size_t)(dh * 16 + (lane >> 2)) * SEQ_ + kc * 32 + (lane & 3) * 8];
      gstep[i] = 64;  // advance 64 keys along seq
    }
  }

  f32x4 o[4];
  float lsum[4] = {0.f, 0.f, 0.f, 0.f};
#pragma unroll
  for (int c = 0; c < 4; c++) o[c] = f32x4{0.f, 0.f, 0.f, 0.f};
  unsigned short* Pw = &Pl[w][0];

  for (int kt = 0; kt < SEQ_ / 64; kt++) {
#pragma unroll
    for (int i = 0; i < 4; i++) {
      gload_lds16(gsrc[i], ldst[i]);
      gsrc[i] += gstep[i];
    }
    __syncthreads();  // K/V tile resident (barrier drains vmcnt)
    f32x4 s[4];
#pragma unroll
    for (int kn = 0; kn < 4; kn++) {
      const bf16x8 kf0 = *(const bf16x8*)&Kl[0][kn * 16 + l15][quad * 8];
      const bf16x8 kf1 = *(const bf16x8*)&Kl[1][kn * 16 + l15][quad * 8];
      s[kn] = __builtin_amdgcn_mfma_f32_16x16x32_bf16(qa0, kf0, f32x4{0.f, 0.f, 0.f, 0.f}, 0, 0, 0);
      s[kn] = __builtin_amdgcn_mfma_f32_16x16x32_bf16(qa1, kf1, s[kn], 0, 0, 0);
    }
#pragma unroll
    for (int kn = 0; kn < 4; kn++)
#pragma unroll
      for (int r = 0; r < 4; r++) {
        const float p = __expf(s[kn][r] - M);
        lsum[r] += p;
        Pw[(quad * 4 + r) * PLD_ + kn * 16 + l15] = f2bf(p);  // C-layout row, col < 64
      }
    asm volatile("s_waitcnt lgkmcnt(0)" ::: "memory");
    const bf16x8 pa0 = *(const bf16x8*)&Pw[l15 * PLD_ + quad * 8];       // keys 0..31
    const bf16x8 pa1 = *(const bf16x8*)&Pw[l15 * PLD_ + 32 + quad * 8];  // keys 32..63
#pragma unroll
    for (int c = 0; c < 4; c++) {
      const bf16x8 vf0 = *(const bf16x8*)&Vl[0][c * 16 + l15][quad * 8];
      const bf16x8 vf1 = *(const bf16x8*)&Vl[1][c * 16 + l15][quad * 8];
      o[c] = __builtin_amdgcn_mfma_f32_16x16x32_bf16(pa0, vf0, o[c], 0, 0, 0);
      o[c] = __builtin_amdgcn_mfma_f32_16x16x32_bf16(pa1, vf1, o[c], 0, 0, 0);
    }
    __syncthreads();  // protect K/V LDS before next DMA
  }

#pragma unroll
  for (int r = 0; r < 4; r++) {
    lsum[r] += __shfl_xor(lsum[r], 1);
    lsum[r] += __shfl_xor(lsum[r], 2);
    lsum[r] += __shfl_xor(lsum[r], 4);
    lsum[r] += __shfl_xor(lsum[r], 8);
    lsum[r] = 1.0f / lsum[r];
  }
  const int b = bh >> 4, h = bh & 15;
#pragma unroll
  for (int c = 0; c < 4; c++)
#pragma unroll
    for (int r = 0; r < 4; r++) {
      const int row = q0 + quad * 4 + r;
      O[((size_t)(b * SEQ_ + row)) * DIM_ + h * 64 + c * 16 + l15] =
          f2bf(o[c][r] * lsum[r]);
    }
}

extern "C" void kernel_launch(void* const* d_in, const int* in_sizes, int n_in,
                              void* d_out, int out_size, void* d_ws, size_t ws_size,
                              hipStream_t stream) {
  const float* x      = (const float*)d_in[0];
  const float* w_qkv  = (const float*)d_in[1];
  const float* b_qkv  = (const float*)d_in[2];
  const float* w_proj = (const float*)d_in[3];
  const float* b_proj = (const float*)d_in[4];
  const float* g1     = (const float*)d_in[5];
  const float* g2     = (const float*)d_in[6];
  const float* gq     = (const float*)d_in[7];
  const float* gk     = (const float*)d_in[8];
  const float* w_fc1  = (const float*)d_in[9];
  const float* b_fc1  = (const float*)d_in[10];
  const float* w_fc2  = (const float*)d_in[11];
  const float* b_fc2  = (const float*)d_in[12];
  float* out = (float*)d_out;

  char* p = (char*)d_ws;
  auto alloc = [&](size_t bytes) {
    char* r = p;
    p += (bytes + 255) & ~(size_t)255;
    return r;
  };
  unsigned short* wqkvT  = (unsigned short*)alloc(3072ull * 1024 * 2);
  unsigned short* wprojT = (unsigned short*)alloc(1024ull * 1024 * 2);
  unsigned short* wfc1T  = (unsigned short*)alloc(4096ull * 1024 * 2);
  unsigned short* wfc2T  = (unsigned short*)alloc(1024ull * 4096 * 2);
  unsigned short* h1     = (unsigned short*)alloc(4096ull * 1024 * 2);  // also Obuf
  char* big = alloc(4096ull * 3072 * 4);  // qkv f32; later reused as h3 bf16
  float* qkvf = (float*)big;
  unsigned short* h3 = (unsigned short*)big;
  unsigned short* QsB = (unsigned short*)alloc(32ull * SEQ_ * HD_ * 2);
  unsigned short* KsB = (unsigned short*)alloc(32ull * SEQ_ * HD_ * 2);
  unsigned short* VTB = (unsigned short*)alloc(32ull * SEQ_ * HD_ * 2);
  float* x2 = (float*)alloc(4096ull * 1024 * 4);
  unsigned short* h2 = (unsigned short*)alloc(4096ull * 1024 * 2);
  unsigned short* Obuf = h1;

  transpose_cvt<<<dim3(3072 / 32, 1024 / 32), 256, 0, stream>>>(w_qkv, wqkvT, 1024, 3072);
  transpose_cvt<<<dim3(1024 / 32, 1024 / 32), 256, 0, stream>>>(w_proj, wprojT, 1024, 1024);
  transpose_cvt<<<dim3(4096 / 32, 1024 / 32), 256, 0, stream>>>(w_fc1, wfc1T, 1024, 4096);
  transpose_cvt<<<dim3(1024 / 32, 4096 / 32), 256, 0, stream>>>(w_fc2, wfc2T, 4096, 1024);
  rmsnorm_k<<<4096, 256, 0, stream>>>(x, g1, h1);
  gemm_bf16<0><<<dim3(3072 / 128, 4096 / 128), 256, 0, stream>>>(
      h1, wqkvT, b_qkv, nullptr, qkvf, 4096, 3072, 1024);
  qkv_post<<<16384, 256, 0, stream>>>(qkvf, gq, gk, QsB, KsB, VTB);
  attn_fwd<<<dim3(32, 32), 256, 0, stream>>>(QsB, KsB, VTB, gq, gk, Obuf);
  gemm_bf16<1><<<dim3(1024 / 128, 4096 / 128), 256, 0, stream>>>(
      Obuf, wprojT, b_proj, x, x2, 4096, 1024, 1024);
  rmsnorm_k<<<4096, 256, 0, stream>>>(x2, g2, h2);
  gemm_bf16<2><<<dim3(4096 / 128, 4096 / 128), 256, 0, stream>>>(
      h2, wfc1T, b_fc1, nullptr, h3, 4096, 4096, 1024);
  gemm_bf16<1><<<dim3(1024 / 128, 4096 / 128), 256, 0, stream>>>(
      h3, wfc2T, b_fc2, x2, out, 4096, 1024, 4096);
}

// Round 4
// 426.451 us; speedup vs baseline: 1.3754x; 1.0053x over previous
//
#include <hip/hip_runtime.h>
#include <stdint.h>

#define SEQ_ 2048
#define DIM_ 1024
#define HD_ 64
#define NH_ 16

typedef __bf16 bf16x8 __attribute__((ext_vector_type(8)));
typedef float f32x4 __attribute__((ext_vector_type(4)));
typedef __attribute__((address_space(1))) unsigned int as1_uint;
typedef __attribute__((address_space(3))) unsigned int as3_uint;

__device__ __forceinline__ unsigned short f2bf(float f) {
  unsigned u = __builtin_bit_cast(unsigned, f);
  u += 0x7fffu + ((u >> 16) & 1u);
  return (unsigned short)(u >> 16);
}
__device__ __forceinline__ float bf2f(unsigned short u) {
  return __builtin_bit_cast(float, ((unsigned)u) << 16);
}

// async global->LDS, 16B per lane. LDS dest is wave-uniform base + lane*16.
__device__ __forceinline__ void gload_lds16(const void* g, void* l) {
  __builtin_amdgcn_global_load_lds(
      reinterpret_cast<as1_uint*>(reinterpret_cast<uintptr_t>(g)),
      reinterpret_cast<as3_uint*>(
          static_cast<unsigned int>(reinterpret_cast<uintptr_t>(l))),
      16, 0, 0);
}

// ---------------- weight transpose + fp32->bf16 convert: Wt[n][k] = W[k][n]
__global__ __launch_bounds__(256) void transpose_cvt(
    const float* __restrict__ W, unsigned short* __restrict__ Wt, int K, int N) {
  __shared__ float t[32][33];
  const int tx = threadIdx.x & 31, ty = threadIdx.x >> 5;  // ty 0..7
  const int n0 = blockIdx.x * 32, k0 = blockIdx.y * 32;
#pragma unroll
  for (int i = 0; i < 4; i++)
    t[ty + i * 8][tx] = W[(size_t)(k0 + ty + i * 8) * N + n0 + tx];
  __syncthreads();
#pragma unroll
  for (int i = 0; i < 4; i++)
    Wt[(size_t)(n0 + ty + i * 8) * K + k0 + tx] = f2bf(t[tx][ty + i * 8]);
}

// ---------------- rmsnorm over DIM: out = x/max(||x||,eps)*32*g  (bf16)
__global__ __launch_bounds__(256) void rmsnorm_k(
    const float* __restrict__ x, const float* __restrict__ g,
    unsigned short* __restrict__ out) {
  const int row = blockIdx.x;
  const float4* xr = (const float4*)(x + (size_t)row * DIM_);
  float4 v = xr[threadIdx.x];
  float ss = v.x * v.x + v.y * v.y + v.z * v.z + v.w * v.w;
  ss += __shfl_xor(ss, 1);  ss += __shfl_xor(ss, 2);  ss += __shfl_xor(ss, 4);
  ss += __shfl_xor(ss, 8);  ss += __shfl_xor(ss, 16); ss += __shfl_xor(ss, 32);
  __shared__ float red[4];
  if ((threadIdx.x & 63) == 0) red[threadIdx.x >> 6] = ss;
  __syncthreads();
  float tot = red[0] + red[1] + red[2] + red[3];
  float sc = 32.0f * g[0] / fmaxf(sqrtf(tot), 1e-12f);
  unsigned short* orow = out + (size_t)row * DIM_;
  const int b4 = threadIdx.x * 4;
  orow[b4 + 0] = f2bf(v.x * sc);
  orow[b4 + 1] = f2bf(v.y * sc);
  orow[b4 + 2] = f2bf(v.z * sc);
  orow[b4 + 3] = f2bf(v.w * sc);
}

// ---------------- GEMM: C[M,N] = A[M,K]@Bt[N,K]^T, split-K over gridDim.z
// EPI: 0 = bias, bf16 out; 1 = bias + residual, f32 out;
//      2 = bias + gelu, bf16 out; 3 = raw f32 partial at z-offset (no bias)
template <int EPI>
__global__ __launch_bounds__(256, 2) void gemm_bf16(
    const unsigned short* __restrict__ A, const unsigned short* __restrict__ Bt,
    const float* __restrict__ bias, const float* __restrict__ res,
    void* __restrict__ Cout, int M, int N, int K) {
  __shared__ __align__(16) unsigned short As[128 * 32];
  __shared__ __align__(16) unsigned short Bs[128 * 32];
  const int tid = threadIdx.x;
  const int w = tid >> 6, lane = tid & 63;
  const int wm = w >> 1, wn = w & 1;
  const int quad = lane >> 4, l15 = lane & 15;
  const int bn = blockIdx.x, bm = blockIdx.y;
  const int Kchunk = K / gridDim.z;
  const int kbeg = blockIdx.z * Kchunk;

  f32x4 acc[4][4];
#pragma unroll
  for (int i = 0; i < 4; i++)
#pragma unroll
    for (int j = 0; j < 4; j++) acc[i][j] = f32x4{0.f, 0.f, 0.f, 0.f};

  const int r0 = w * 16 + (lane >> 2);
  const int c0 = (lane & 3) * 8;
  const unsigned short* gA0 = A + (size_t)(bm * 128 + r0) * K + kbeg + c0;
  const unsigned short* gA1 = gA0 + (size_t)64 * K;
  const unsigned short* gB0 = Bt + (size_t)(bn * 128 + r0) * K + kbeg + c0;
  const unsigned short* gB1 = gB0 + (size_t)64 * K;
  unsigned short* lA0 = As + w * 512;
  unsigned short* lA1 = As + 2048 + w * 512;
  unsigned short* lB0 = Bs + w * 512;
  unsigned short* lB1 = Bs + 2048 + w * 512;

  for (int kk = 0; kk < Kchunk; kk += 32) {
    gload_lds16(gA0, lA0);
    gload_lds16(gA1, lA1);
    gload_lds16(gB0, lB0);
    gload_lds16(gB1, lB1);
    gA0 += 32; gA1 += 32; gB0 += 32; gB1 += 32;
    __syncthreads();
    bf16x8 af[4], bf[4];
#pragma unroll
    for (int i = 0; i < 4; i++) {
      af[i] = *(const bf16x8*)&As[(wm * 64 + i * 16 + l15) * 32 + quad * 8];
      bf[i] = *(const bf16x8*)&Bs[(wn * 64 + i * 16 + l15) * 32 + quad * 8];
    }
#pragma unroll
    for (int i = 0; i < 4; i++)
#pragma unroll
      for (int j = 0; j < 4; j++)
        acc[i][j] = __builtin_amdgcn_mfma_f32_16x16x32_bf16(af[i], bf[j], acc[i][j], 0, 0, 0);
    __syncthreads();
  }

  const int rowb = bm * 128 + wm * 64;
  const int colb = bn * 128 + wn * 64;
  float* Cz = (float*)Cout + (size_t)blockIdx.z * M * N;  // EPI3 partial slab
#pragma unroll
  for (int i = 0; i < 4; i++) {
#pragma unroll
    for (int j = 0; j < 4; j++) {
      const int col = colb + j * 16 + l15;
      const float bv = (EPI == 3) ? 0.0f : bias[col];
#pragma unroll
      for (int r = 0; r < 4; r++) {
        const int row = rowb + i * 16 + quad * 4 + r;
        const size_t idx = (size_t)row * N + col;
        float v = acc[i][j][r] + bv;
        if (EPI == 0) {
          ((unsigned short*)Cout)[idx] = f2bf(v);
        } else if (EPI == 1) {
          ((float*)Cout)[idx] = v + res[idx];
        } else if (EPI == 2) {
          float t = tanhf(0.7978845608028654f * (v + 0.044715f * v * v * v));
          ((unsigned short*)Cout)[idx] = f2bf(0.5f * v * (1.0f + t));
        } else {
          Cz[idx] = v;
        }
      }
    }
  }
}

// ---------------- split-K reduce: out = res + bias + sum_z part[z]
__global__ __launch_bounds__(256) void reduce_splitk(
    const float* __restrict__ part, int S, const float* __restrict__ res,
    const float* __restrict__ bias, float* __restrict__ out, int N, size_t MN) {
  const size_t n4 = MN >> 2;
  const size_t i = (size_t)blockIdx.x * 256 + threadIdx.x;
  if (i >= n4) return;
  float4 a = ((const float4*)res)[i];
  float4 b = ((const float4*)bias)[i % (size_t)(N >> 2)];
  float sx = a.x + b.x, sy = a.y + b.y, sz = a.z + b.z, sw = a.w + b.w;
  for (int z = 0; z < S; z++) {
    float4 p = ((const float4*)part)[z * n4 + i];
    sx += p.x; sy += p.y; sz += p.z; sw += p.w;
  }
  ((float4*)out)[i] = make_float4(sx, sy, sz, sw);
}

// ---------------- qkv postprocess (bf16 in): per-head L2 norm of q,k; v transposed
__global__ __launch_bounds__(256) void qkv_post(
    const unsigned short* __restrict__ qkv, const float* __restrict__ gq,
    const float* __restrict__ gk, unsigned short* __restrict__ Qs,
    unsigned short* __restrict__ Ks, unsigned short* __restrict__ VT) {
  const int item = blockIdx.x * 4 + (threadIdx.x >> 6);
  const int lane = threadIdx.x & 63;
  const int h = item & 15;
  const int rn = item >> 4;  // b*SEQ+n
  const int b = rn >> 11, n = rn & 2047;
  const unsigned short* base = qkv + (size_t)rn * 3072 + h * 64;
  const float qv = bf2f(base[lane]);
  const float kv = bf2f(base[1024 + lane]);
  const float vv = bf2f(base[2048 + lane]);
  float sq = qv * qv, sk = kv * kv;
  sq += __shfl_xor(sq, 1);  sk += __shfl_xor(sk, 1);
  sq += __shfl_xor(sq, 2);  sk += __shfl_xor(sk, 2);
  sq += __shfl_xor(sq, 4);  sk += __shfl_xor(sk, 4);
  sq += __shfl_xor(sq, 8);  sk += __shfl_xor(sk, 8);
  sq += __shfl_xor(sq, 16); sk += __shfl_xor(sk, 16);
  sq += __shfl_xor(sq, 32); sk += __shfl_xor(sk, 32);
  const float qs = qv / fmaxf(sqrtf(sq), 1e-12f) * gq[0];
  const float ks = kv / fmaxf(sqrtf(sk), 1e-12f) * (8.0f * gk[0]);
  const int bh = b * 16 + h;
  Qs[((size_t)bh * SEQ_ + n) * HD_ + lane] = f2bf(qs);
  Ks[((size_t)bh * SEQ_ + n) * HD_ + lane] = f2bf(ks);
  VT[((size_t)bh * HD_ + lane) * SEQ_ + n] = f2bf(vv);
}

// ---------------- flash attention, fixed-max softmax (scores bounded by 8|gq*gk|)
#define PLD_ 72  // P row stride in shorts; must be >= 64 (16x64 tile)
__global__ __launch_bounds__(256) void attn_fwd(
    const unsigned short* __restrict__ Qs, const unsigned short* __restrict__ Ks,
    const unsigned short* __restrict__ VT, const float* __restrict__ gq,
    const float* __restrict__ gk, unsigned short* __restrict__ O) {
  __shared__ __align__(16) unsigned short Kl[2][64][32];
  __shared__ __align__(16) unsigned short Vl[2][64][32];
  __shared__ __align__(16) unsigned short Pl[4][16 * PLD_];
  const int bh = blockIdx.x, qt = blockIdx.y;
  const int w = threadIdx.x >> 6, lane = threadIdx.x & 63;
  const int quad = lane >> 4, l15 = lane & 15;
  const float M = 8.0f * fabsf(gq[0] * gk[0]);
  const unsigned short* Qb = Qs + (size_t)bh * SEQ_ * HD_;
  const unsigned short* Kb = Ks + (size_t)bh * SEQ_ * HD_;
  const unsigned short* Vb = VT + (size_t)bh * HD_ * SEQ_;
  const int q0 = qt * 64 + w * 16;
  const bf16x8 qa0 = *(const bf16x8*)&Qb[(q0 + l15) * HD_ + quad * 8];
  const bf16x8 qa1 = *(const bf16x8*)&Qb[(q0 + l15) * HD_ + 32 + quad * 8];

  const unsigned short* gsrc[4];
  unsigned short* ldst[4];
  int gstep[4];
#pragma unroll
  for (int i = 0; i < 4; i++) {
    const int idx = w * 4 + i;
    if (idx < 8) {
      const int kc = idx >> 2, kh = idx & 3;
      ldst[i] = &Kl[kc][kh * 16][0];
      gsrc[i] = &Kb[(size_t)(kh * 16 + (lane >> 2)) * HD_ + kc * 32 + (lane & 3) * 8];
      gstep[i] = 64 * HD_;
    } else {
      const int j = idx - 8;
      const int kc = j >> 2, dh = j & 3;
      ldst[i] = &Vl[kc][dh * 16][0];
      gsrc[i] = &Vb[(size_t)(dh * 16 + (lane >> 2)) * SEQ_ + kc * 32 + (lane & 3) * 8];
      gstep[i] = 64;
    }
  }

  f32x4 o[4];
  float lsum[4] = {0.f, 0.f, 0.f, 0.f};
#pragma unroll
  for (int c = 0; c < 4; c++) o[c] = f32x4{0.f, 0.f, 0.f, 0.f};
  unsigned short* Pw = &Pl[w][0];

  for (int kt = 0; kt < SEQ_ / 64; kt++) {
#pragma unroll
    for (int i = 0; i < 4; i++) {
      gload_lds16(gsrc[i], ldst[i]);
      gsrc[i] += gstep[i];
    }
    __syncthreads();
    f32x4 s[4];
#pragma unroll
    for (int kn = 0; kn < 4; kn++) {
      const bf16x8 kf0 = *(const bf16x8*)&Kl[0][kn * 16 + l15][quad * 8];
      const bf16x8 kf1 = *(const bf16x8*)&Kl[1][kn * 16 + l15][quad * 8];
      s[kn] = __builtin_amdgcn_mfma_f32_16x16x32_bf16(qa0, kf0, f32x4{0.f, 0.f, 0.f, 0.f}, 0, 0, 0);
      s[kn] = __builtin_amdgcn_mfma_f32_16x16x32_bf16(qa1, kf1, s[kn], 0, 0, 0);
    }
#pragma unroll
    for (int kn = 0; kn < 4; kn++)
#pragma unroll
      for (int r = 0; r < 4; r++) {
        const float p = __expf(s[kn][r] - M);
        lsum[r] += p;
        Pw[(quad * 4 + r) * PLD_ + kn * 16 + l15] = f2bf(p);
      }
    asm volatile("s_waitcnt lgkmcnt(0)" ::: "memory");
    const bf16x8 pa0 = *(const bf16x8*)&Pw[l15 * PLD_ + quad * 8];
    const bf16x8 pa1 = *(const bf16x8*)&Pw[l15 * PLD_ + 32 + quad * 8];
#pragma unroll
    for (int c = 0; c < 4; c++) {
      const bf16x8 vf0 = *(const bf16x8*)&Vl[0][c * 16 + l15][quad * 8];
      const bf16x8 vf1 = *(const bf16x8*)&Vl[1][c * 16 + l15][quad * 8];
      o[c] = __builtin_amdgcn_mfma_f32_16x16x32_bf16(pa0, vf0, o[c], 0, 0, 0);
      o[c] = __builtin_amdgcn_mfma_f32_16x16x32_bf16(pa1, vf1, o[c], 0, 0, 0);
    }
    __syncthreads();
  }

#pragma unroll
  for (int r = 0; r < 4; r++) {
    lsum[r] += __shfl_xor(lsum[r], 1);
    lsum[r] += __shfl_xor(lsum[r], 2);
    lsum[r] += __shfl_xor(lsum[r], 4);
    lsum[r] += __shfl_xor(lsum[r], 8);
    lsum[r] = 1.0f / lsum[r];
  }
  const int b = bh >> 4, h = bh & 15;
#pragma unroll
  for (int c = 0; c < 4; c++)
#pragma unroll
    for (int r = 0; r < 4; r++) {
      const int row = q0 + quad * 4 + r;
      O[((size_t)(b * SEQ_ + row)) * DIM_ + h * 64 + c * 16 + l15] =
          f2bf(o[c][r] * lsum[r]);
    }
}

extern "C" void kernel_launch(void* const* d_in, const int* in_sizes, int n_in,
                              void* d_out, int out_size, void* d_ws, size_t ws_size,
                              hipStream_t stream) {
  const float* x      = (const float*)d_in[0];
  const float* w_qkv  = (const float*)d_in[1];
  const float* b_qkv  = (const float*)d_in[2];
  const float* w_proj = (const float*)d_in[3];
  const float* b_proj = (const float*)d_in[4];
  const float* g1     = (const float*)d_in[5];
  const float* g2     = (const float*)d_in[6];
  const float* gq     = (const float*)d_in[7];
  const float* gk     = (const float*)d_in[8];
  const float* w_fc1  = (const float*)d_in[9];
  const float* b_fc1  = (const float*)d_in[10];
  const float* w_fc2  = (const float*)d_in[11];
  const float* b_fc2  = (const float*)d_in[12];
  float* out = (float*)d_out;

  char* p = (char*)d_ws;
  auto alloc = [&](size_t bytes) {
    char* r = p;
    p += (bytes + 255) & ~(size_t)255;
    return r;
  };
  const size_t MB = 1ull << 20;
  unsigned short* wqkvT  = (unsigned short*)alloc(3072ull * 1024 * 2);
  unsigned short* wprojT = (unsigned short*)alloc(1024ull * 1024 * 2);
  unsigned short* wfc1T  = (unsigned short*)alloc(4096ull * 1024 * 2);
  unsigned short* wfc2T  = (unsigned short*)alloc(1024ull * 4096 * 2);
  unsigned short* h1     = (unsigned short*)alloc(4096ull * 1024 * 2);  // also Obuf
  unsigned short* QsB = (unsigned short*)alloc(32ull * SEQ_ * HD_ * 2);
  unsigned short* KsB = (unsigned short*)alloc(32ull * SEQ_ * HD_ * 2);
  unsigned short* VTB = (unsigned short*)alloc(32ull * SEQ_ * HD_ * 2);
  float* x2 = (float*)alloc(4096ull * 1024 * 4);
  unsigned short* h2 = (unsigned short*)alloc(4096ull * 1024 * 2);
  // remaining scratch = "big", multi-phase:
  //   phase A: qkv bf16 [0,24MB)   phase B: proj partials [0,32MB)
  //   phase C: h3 bf16 [0,32MB)    phase D: fc2 partials [32MB, 32+16*S)
  char* big = p;
  const size_t rem = ws_size - (size_t)(p - (char*)d_ws);
  unsigned short* qkvb = (unsigned short*)big;
  unsigned short* h3   = (unsigned short*)big;
  float* proj_part = (float*)big;
  float* fc2_part  = (float*)(big + 32 * MB);
  const int S_pr  = rem >= 64 * MB ? 2 : 1;
  const int S_fc2 = rem >= 96 * MB ? 4 : (rem >= 64 * MB ? 2 : 1);
  unsigned short* Obuf = h1;
  const size_t MN = 4096ull * 1024;

  transpose_cvt<<<dim3(3072 / 32, 1024 / 32), 256, 0, stream>>>(w_qkv, wqkvT, 1024, 3072);
  transpose_cvt<<<dim3(1024 / 32, 1024 / 32), 256, 0, stream>>>(w_proj, wprojT, 1024, 1024);
  transpose_cvt<<<dim3(4096 / 32, 1024 / 32), 256, 0, stream>>>(w_fc1, wfc1T, 1024, 4096);
  transpose_cvt<<<dim3(1024 / 32, 4096 / 32), 256, 0, stream>>>(w_fc2, wfc2T, 4096, 1024);
  rmsnorm_k<<<4096, 256, 0, stream>>>(x, g1, h1);
  // qkv = h1 @ w_qkv + b_qkv  (bf16 out)
  gemm_bf16<0><<<dim3(3072 / 128, 4096 / 128), 256, 0, stream>>>(
      h1, wqkvT, b_qkv, nullptr, qkvb, 4096, 3072, 1024);
  qkv_post<<<16384, 256, 0, stream>>>(qkvb, gq, gk, QsB, KsB, VTB);
  attn_fwd<<<dim3(32, 32), 256, 0, stream>>>(QsB, KsB, VTB, gq, gk, Obuf);
  // proj: x2 = x + Obuf @ w_proj + b_proj
  if (S_pr > 1) {
    gemm_bf16<3><<<dim3(1024 / 128, 4096 / 128, S_pr), 256, 0, stream>>>(
        Obuf, wprojT, b_proj, nullptr, proj_part, 4096, 1024, 1024);
    reduce_splitk<<<(MN / 4 + 255) / 256, 256, 0, stream>>>(
        proj_part, S_pr, x, b_proj, x2, 1024, MN);
  } else {
    gemm_bf16<1><<<dim3(1024 / 128, 4096 / 128), 256, 0, stream>>>(
        Obuf, wprojT, b_proj, x, x2, 4096, 1024, 1024);
  }
  rmsnorm_k<<<4096, 256, 0, stream>>>(x2, g2, h2);
  // fc1: h3 = gelu(h2 @ w_fc1 + b_fc1)
  gemm_bf16<2><<<dim3(4096 / 128, 4096 / 128), 256, 0, stream>>>(
      h2, wfc1T, b_fc1, nullptr, h3, 4096, 4096, 1024);
  // fc2: out = x2 + h3 @ w_fc2 + b_fc2
  if (S_fc2 > 1) {
    gemm_bf16<3><<<dim3(1024 / 128, 4096 / 128, S_fc2), 256, 0, stream>>>(
        h3, wfc2T, b_fc2, nullptr, fc2_part, 4096, 1024, 4096);
    reduce_splitk<<<(MN / 4 + 255) / 256, 256, 0, stream>>>(
        fc2_part, S_fc2, x2, b_fc2, out, 1024, MN);
  } else {
    gemm_bf16<1><<<dim3(1024 / 128, 4096 / 128), 256, 0, stream>>>(
        h3, wfc2T, b_fc2, x2, out, 4096, 1024, 4096);
  }
}

// Round 5
// 414.435 us; speedup vs baseline: 1.4153x; 1.0290x over previous
//
#include <hip/hip_runtime.h>
#include <stdint.h>

#define SEQ_ 2048
#define DIM_ 1024
#define HD_ 64
#define NH_ 16

typedef __bf16 bf16x8 __attribute__((ext_vector_type(8)));
typedef float f32x4 __attribute__((ext_vector_type(4)));
typedef __attribute__((address_space(1))) unsigned int as1_uint;
typedef __attribute__((address_space(3))) unsigned int as3_uint;

__device__ __forceinline__ unsigned short f2bf(float f) {
  unsigned u = __builtin_bit_cast(unsigned, f);
  u += 0x7fffu + ((u >> 16) & 1u);
  return (unsigned short)(u >> 16);
}
__device__ __forceinline__ float bf2f(unsigned short u) {
  return __builtin_bit_cast(float, ((unsigned)u) << 16);
}
// pack two f32 -> two bf16 (truncate) in ONE v_perm_b32
__device__ __forceinline__ unsigned pk_bf2(float lo, float hi) {
  return __builtin_amdgcn_perm(__builtin_bit_cast(unsigned, hi),
                               __builtin_bit_cast(unsigned, lo), 0x07060302u);
}

// async global->LDS, 16B per lane. LDS dest is wave-uniform base + lane*16.
__device__ __forceinline__ void gload_lds16(const void* g, void* l) {
  __builtin_amdgcn_global_load_lds(
      reinterpret_cast<as1_uint*>(reinterpret_cast<uintptr_t>(g)),
      reinterpret_cast<as3_uint*>(
          static_cast<unsigned int>(reinterpret_cast<uintptr_t>(l))),
      16, 0, 0);
}

// ---------------- weight transpose + fp32->bf16 convert: Wt[n][k] = W[k][n]
__global__ __launch_bounds__(256) void transpose_cvt(
    const float* __restrict__ W, unsigned short* __restrict__ Wt, int K, int N) {
  __shared__ float t[32][33];
  const int tx = threadIdx.x & 31, ty = threadIdx.x >> 5;  // ty 0..7
  const int n0 = blockIdx.x * 32, k0 = blockIdx.y * 32;
#pragma unroll
  for (int i = 0; i < 4; i++)
    t[ty + i * 8][tx] = W[(size_t)(k0 + ty + i * 8) * N + n0 + tx];
  __syncthreads();
#pragma unroll
  for (int i = 0; i < 4; i++)
    Wt[(size_t)(n0 + ty + i * 8) * K + k0 + tx] = f2bf(t[tx][ty + i * 8]);
}

// ---------------- rmsnorm over DIM: out = x/max(||x||,eps)*32*g  (bf16)
__global__ __launch_bounds__(256) void rmsnorm_k(
    const float* __restrict__ x, const float* __restrict__ g,
    unsigned short* __restrict__ out) {
  const int row = blockIdx.x;
  const float4* xr = (const float4*)(x + (size_t)row * DIM_);
  float4 v = xr[threadIdx.x];
  float ss = v.x * v.x + v.y * v.y + v.z * v.z + v.w * v.w;
  ss += __shfl_xor(ss, 1);  ss += __shfl_xor(ss, 2);  ss += __shfl_xor(ss, 4);
  ss += __shfl_xor(ss, 8);  ss += __shfl_xor(ss, 16); ss += __shfl_xor(ss, 32);
  __shared__ float red[4];
  if ((threadIdx.x & 63) == 0) red[threadIdx.x >> 6] = ss;
  __syncthreads();
  float tot = red[0] + red[1] + red[2] + red[3];
  float sc = 32.0f * g[0] / fmaxf(sqrtf(tot), 1e-12f);
  unsigned short* orow = out + (size_t)row * DIM_;
  const int b4 = threadIdx.x * 4;
  orow[b4 + 0] = f2bf(v.x * sc);
  orow[b4 + 1] = f2bf(v.y * sc);
  orow[b4 + 2] = f2bf(v.z * sc);
  orow[b4 + 3] = f2bf(v.w * sc);
}

// ---------------- GEMM: C[M,N] = A[M,K]@Bt[N,K]^T, split-K over gridDim.z
// EPI: 0 = bias, bf16 out; 1 = bias + residual, f32 out;
//      2 = bias + gelu, bf16 out; 3 = raw f32 partial at z-offset (no bias)
template <int EPI>
__global__ __launch_bounds__(256, 2) void gemm_bf16(
    const unsigned short* __restrict__ A, const unsigned short* __restrict__ Bt,
    const float* __restrict__ bias, const float* __restrict__ res,
    void* __restrict__ Cout, int M, int N, int K) {
  __shared__ __align__(16) unsigned short As[128 * 32];
  __shared__ __align__(16) unsigned short Bs[128 * 32];
  const int tid = threadIdx.x;
  const int w = tid >> 6, lane = tid & 63;
  const int wm = w >> 1, wn = w & 1;
  const int quad = lane >> 4, l15 = lane & 15;
  const int bn = blockIdx.x, bm = blockIdx.y;
  const int Kchunk = K / gridDim.z;
  const int kbeg = blockIdx.z * Kchunk;

  f32x4 acc[4][4];
#pragma unroll
  for (int i = 0; i < 4; i++)
#pragma unroll
    for (int j = 0; j < 4; j++) acc[i][j] = f32x4{0.f, 0.f, 0.f, 0.f};

  const int r0 = w * 16 + (lane >> 2);
  const int c0 = (lane & 3) * 8;
  const unsigned short* gA0 = A + (size_t)(bm * 128 + r0) * K + kbeg + c0;
  const unsigned short* gA1 = gA0 + (size_t)64 * K;
  const unsigned short* gB0 = Bt + (size_t)(bn * 128 + r0) * K + kbeg + c0;
  const unsigned short* gB1 = gB0 + (size_t)64 * K;
  unsigned short* lA0 = As + w * 512;
  unsigned short* lA1 = As + 2048 + w * 512;
  unsigned short* lB0 = Bs + w * 512;
  unsigned short* lB1 = Bs + 2048 + w * 512;

  for (int kk = 0; kk < Kchunk; kk += 32) {
    gload_lds16(gA0, lA0);
    gload_lds16(gA1, lA1);
    gload_lds16(gB0, lB0);
    gload_lds16(gB1, lB1);
    gA0 += 32; gA1 += 32; gB0 += 32; gB1 += 32;
    __syncthreads();
    bf16x8 af[4], bf[4];
#pragma unroll
    for (int i = 0; i < 4; i++) {
      af[i] = *(const bf16x8*)&As[(wm * 64 + i * 16 + l15) * 32 + quad * 8];
      bf[i] = *(const bf16x8*)&Bs[(wn * 64 + i * 16 + l15) * 32 + quad * 8];
    }
#pragma unroll
    for (int i = 0; i < 4; i++)
#pragma unroll
      for (int j = 0; j < 4; j++)
        acc[i][j] = __builtin_amdgcn_mfma_f32_16x16x32_bf16(af[i], bf[j], acc[i][j], 0, 0, 0);
    __syncthreads();
  }

  const int rowb = bm * 128 + wm * 64;
  const int colb = bn * 128 + wn * 64;
  float* Cz = (float*)Cout + (size_t)blockIdx.z * M * N;  // EPI3 partial slab
#pragma unroll
  for (int i = 0; i < 4; i++) {
#pragma unroll
    for (int j = 0; j < 4; j++) {
      const int col = colb + j * 16 + l15;
      const float bv = (EPI == 3) ? 0.0f : bias[col];
#pragma unroll
      for (int r = 0; r < 4; r++) {
        const int row = rowb + i * 16 + quad * 4 + r;
        const size_t idx = (size_t)row * N + col;
        float v = acc[i][j][r] + bv;
        if (EPI == 0) {
          ((unsigned short*)Cout)[idx] = f2bf(v);
        } else if (EPI == 1) {
          ((float*)Cout)[idx] = v + res[idx];
        } else if (EPI == 2) {
          float t = tanhf(0.7978845608028654f * (v + 0.044715f * v * v * v));
          ((unsigned short*)Cout)[idx] = f2bf(0.5f * v * (1.0f + t));
        } else {
          Cz[idx] = v;
        }
      }
    }
  }
}

// ---------------- split-K reduce: out = res + bias + sum_z part[z]
__global__ __launch_bounds__(256) void reduce_splitk(
    const float* __restrict__ part, int S, const float* __restrict__ res,
    const float* __restrict__ bias, float* __restrict__ out, int N, size_t MN) {
  const size_t n4 = MN >> 2;
  const size_t i = (size_t)blockIdx.x * 256 + threadIdx.x;
  if (i >= n4) return;
  float4 a = ((const float4*)res)[i];
  float4 b = ((const float4*)bias)[i % (size_t)(N >> 2)];
  float sx = a.x + b.x, sy = a.y + b.y, sz = a.z + b.z, sw = a.w + b.w;
  for (int z = 0; z < S; z++) {
    float4 p = ((const float4*)part)[z * n4 + i];
    sx += p.x; sy += p.y; sz += p.z; sw += p.w;
  }
  ((float4*)out)[i] = make_float4(sx, sy, sz, sw);
}

// ---------------- qkv postprocess (bf16 in): per-head L2 norm of q,k; v transposed
__global__ __launch_bounds__(256) void qkv_post(
    const unsigned short* __restrict__ qkv, const float* __restrict__ gq,
    const float* __restrict__ gk, unsigned short* __restrict__ Qs,
    unsigned short* __restrict__ Ks, unsigned short* __restrict__ VT) {
  const int item = blockIdx.x * 4 + (threadIdx.x >> 6);
  const int lane = threadIdx.x & 63;
  const int h = item & 15;
  const int rn = item >> 4;  // b*SEQ+n
  const int b = rn >> 11, n = rn & 2047;
  const unsigned short* base = qkv + (size_t)rn * 3072 + h * 64;
  const float qv = bf2f(base[lane]);
  const float kv = bf2f(base[1024 + lane]);
  const float vv = bf2f(base[2048 + lane]);
  float sq = qv * qv, sk = kv * kv;
  sq += __shfl_xor(sq, 1);  sk += __shfl_xor(sk, 1);
  sq += __shfl_xor(sq, 2);  sk += __shfl_xor(sk, 2);
  sq += __shfl_xor(sq, 4);  sk += __shfl_xor(sk, 4);
  sq += __shfl_xor(sq, 8);  sk += __shfl_xor(sk, 8);
  sq += __shfl_xor(sq, 16); sk += __shfl_xor(sk, 16);
  sq += __shfl_xor(sq, 32); sk += __shfl_xor(sk, 32);
  const float qs = qv / fmaxf(sqrtf(sq), 1e-12f) * gq[0];
  const float ks = kv / fmaxf(sqrtf(sk), 1e-12f) * (8.0f * gk[0]);
  const int bh = b * 16 + h;
  Qs[((size_t)bh * SEQ_ + n) * HD_ + lane] = f2bf(qs);
  Ks[((size_t)bh * SEQ_ + n) * HD_ + lane] = f2bf(ks);
  VT[((size_t)bh * HD_ + lane) * SEQ_ + n] = f2bf(vv);
}

// ---------------- flash attention v2: S^T via swapped MFMA operands.
// Fixed-max softmax (scores bounded by 8|gq*gk|); per-lane lsum accumulation;
// P packed with v_perm -> ds_write_b64; P row-major [q][key] ld=72 (bank-floor).
#define PLD_ 72
__global__ __launch_bounds__(256) void attn_fwd(
    const unsigned short* __restrict__ Qs, const unsigned short* __restrict__ Ks,
    const unsigned short* __restrict__ VT, const float* __restrict__ gq,
    const float* __restrict__ gk, unsigned short* __restrict__ O) {
  __shared__ __align__(16) unsigned short Kl[2][64][32];  // [d-half][key][d-chunk]
  __shared__ __align__(16) unsigned short Vl[2][64][32];  // [key-half][d][key-chunk]
  __shared__ __align__(16) unsigned short Pl[4][16 * PLD_];  // per-wave [q][key]
  const int bh = blockIdx.x, qt = blockIdx.y;
  const int w = threadIdx.x >> 6, lane = threadIdx.x & 63;
  const int quad = lane >> 4, l15 = lane & 15;
  const float M = 8.0f * fabsf(gq[0] * gk[0]);
  const unsigned short* Qb = Qs + (size_t)bh * SEQ_ * HD_;
  const unsigned short* Kb = Ks + (size_t)bh * SEQ_ * HD_;
  const unsigned short* Vb = VT + (size_t)bh * HD_ * SEQ_;
  const int q0 = qt * 64 + w * 16;
  // Q as B-operand: B[k=d][n=q], lane l15 = q
  const bf16x8 qa0 = *(const bf16x8*)&Qb[(q0 + l15) * HD_ + quad * 8];
  const bf16x8 qa1 = *(const bf16x8*)&Qb[(q0 + l15) * HD_ + 32 + quad * 8];

  const unsigned short* gsrc[4];
  unsigned short* ldst[4];
  int gstep[4];
#pragma unroll
  for (int i = 0; i < 4; i++) {
    const int idx = w * 4 + i;
    if (idx < 8) {
      const int kc = idx >> 2, kh = idx & 3;
      ldst[i] = &Kl[kc][kh * 16][0];
      gsrc[i] = &Kb[(size_t)(kh * 16 + (lane >> 2)) * HD_ + kc * 32 + (lane & 3) * 8];
      gstep[i] = 64 * HD_;
    } else {
      const int j = idx - 8;
      const int kc = j >> 2, dh = j & 3;
      ldst[i] = &Vl[kc][dh * 16][0];
      gsrc[i] = &Vb[(size_t)(dh * 16 + (lane >> 2)) * SEQ_ + kc * 32 + (lane & 3) * 8];
      gstep[i] = 64;
    }
  }

  f32x4 o[4];
  float lacc = 0.0f;  // per-lane: sum of p over this lane's key slice, q = l15
#pragma unroll
  for (int c = 0; c < 4; c++) o[c] = f32x4{0.f, 0.f, 0.f, 0.f};
  unsigned short* Pw = &Pl[w][0];

  for (int kt = 0; kt < SEQ_ / 64; kt++) {
#pragma unroll
    for (int i = 0; i < 4; i++) {
      gload_lds16(gsrc[i], ldst[i]);
      gsrc[i] += gstep[i];
    }
    __syncthreads();
    // S^T[key][q]: A = K-frag (m=key, lane l15 = key-in-block), B = Q-frag
    f32x4 st[4];
#pragma unroll
    for (int kn = 0; kn < 4; kn++) {
      const bf16x8 kf0 = *(const bf16x8*)&Kl[0][kn * 16 + l15][quad * 8];
      const bf16x8 kf1 = *(const bf16x8*)&Kl[1][kn * 16 + l15][quad * 8];
      st[kn] = __builtin_amdgcn_mfma_f32_16x16x32_bf16(kf0, qa0, f32x4{0.f, 0.f, 0.f, 0.f}, 0, 0, 0);
      st[kn] = __builtin_amdgcn_mfma_f32_16x16x32_bf16(kf1, qa1, st[kn], 0, 0, 0);
    }
    // softmax numerators; lane holds keys kn*16+quad*4+r for q=l15
#pragma unroll
    for (int kn = 0; kn < 4; kn++) {
      const float p0 = __expf(st[kn][0] - M);
      const float p1 = __expf(st[kn][1] - M);
      const float p2 = __expf(st[kn][2] - M);
      const float p3 = __expf(st[kn][3] - M);
      lacc += (p0 + p1) + (p2 + p3);
      uint2 pk;
      pk.x = pk_bf2(p0, p1);
      pk.y = pk_bf2(p2, p3);
      *(uint2*)&Pw[l15 * PLD_ + kn * 16 + quad * 4] = pk;  // 4 consecutive keys
    }
    asm volatile("s_waitcnt lgkmcnt(0)" ::: "memory");
    // P as A-operand: A[m=q(l15)][k=key(quad*8+j)]
    const bf16x8 pa0 = *(const bf16x8*)&Pw[l15 * PLD_ + quad * 8];
    const bf16x8 pa1 = *(const bf16x8*)&Pw[l15 * PLD_ + 32 + quad * 8];
#pragma unroll
    for (int c = 0; c < 4; c++) {
      const bf16x8 vf0 = *(const bf16x8*)&Vl[0][c * 16 + l15][quad * 8];
      const bf16x8 vf1 = *(const bf16x8*)&Vl[1][c * 16 + l15][quad * 8];
      o[c] = __builtin_amdgcn_mfma_f32_16x16x32_bf16(pa0, vf0, o[c], 0, 0, 0);
      o[c] = __builtin_amdgcn_mfma_f32_16x16x32_bf16(pa1, vf1, o[c], 0, 0, 0);
    }
    __syncthreads();
  }

  // full softmax denominator for q = l15: reduce across the 4 quads
  lacc += __shfl_xor(lacc, 16);
  lacc += __shfl_xor(lacc, 32);
  const float linv = 1.0f / lacc;
  // o[c][r] is for q = q0 + quad*4 + r: fetch that row's 1/lsum from lane quad*4+r
  float lr[4];
#pragma unroll
  for (int r = 0; r < 4; r++) lr[r] = __shfl(linv, quad * 4 + r);
  const int b = bh >> 4, h = bh & 15;
#pragma unroll
  for (int c = 0; c < 4; c++)
#pragma unroll
    for (int r = 0; r < 4; r++) {
      const int row = q0 + quad * 4 + r;
      O[((size_t)(b * SEQ_ + row)) * DIM_ + h * 64 + c * 16 + l15] =
          f2bf(o[c][r] * lr[r]);
    }
}

extern "C" void kernel_launch(void* const* d_in, const int* in_sizes, int n_in,
                              void* d_out, int out_size, void* d_ws, size_t ws_size,
                              hipStream_t stream) {
  const float* x      = (const float*)d_in[0];
  const float* w_qkv  = (const float*)d_in[1];
  const float* b_qkv  = (const float*)d_in[2];
  const float* w_proj = (const float*)d_in[3];
  const float* b_proj = (const float*)d_in[4];
  const float* g1     = (const float*)d_in[5];
  const float* g2     = (const float*)d_in[6];
  const float* gq     = (const float*)d_in[7];
  const float* gk     = (const float*)d_in[8];
  const float* w_fc1  = (const float*)d_in[9];
  const float* b_fc1  = (const float*)d_in[10];
  const float* w_fc2  = (const float*)d_in[11];
  const float* b_fc2  = (const float*)d_in[12];
  float* out = (float*)d_out;

  char* p = (char*)d_ws;
  auto alloc = [&](size_t bytes) {
    char* r = p;
    p += (bytes + 255) & ~(size_t)255;
    return r;
  };
  const size_t MB = 1ull << 20;
  unsigned short* wqkvT  = (unsigned short*)alloc(3072ull * 1024 * 2);
  unsigned short* wprojT = (unsigned short*)alloc(1024ull * 1024 * 2);
  unsigned short* wfc1T  = (unsigned short*)alloc(4096ull * 1024 * 2);
  unsigned short* wfc2T  = (unsigned short*)alloc(1024ull * 4096 * 2);
  unsigned short* h1     = (unsigned short*)alloc(4096ull * 1024 * 2);  // also Obuf
  unsigned short* QsB = (unsigned short*)alloc(32ull * SEQ_ * HD_ * 2);
  unsigned short* KsB = (unsigned short*)alloc(32ull * SEQ_ * HD_ * 2);
  unsigned short* VTB = (unsigned short*)alloc(32ull * SEQ_ * HD_ * 2);
  float* x2 = (float*)alloc(4096ull * 1024 * 4);
  unsigned short* h2 = (unsigned short*)alloc(4096ull * 1024 * 2);
  char* big = p;
  const size_t rem = ws_size - (size_t)(p - (char*)d_ws);
  unsigned short* qkvb = (unsigned short*)big;
  unsigned short* h3   = (unsigned short*)big;
  float* proj_part = (float*)big;
  float* fc2_part  = (float*)(big + 32 * MB);
  const int S_pr  = rem >= 64 * MB ? 2 : 1;
  const int S_fc2 = rem >= 96 * MB ? 4 : (rem >= 64 * MB ? 2 : 1);
  unsigned short* Obuf = h1;
  const size_t MN = 4096ull * 1024;

  transpose_cvt<<<dim3(3072 / 32, 1024 / 32), 256, 0, stream>>>(w_qkv, wqkvT, 1024, 3072);
  transpose_cvt<<<dim3(1024 / 32, 1024 / 32), 256, 0, stream>>>(w_proj, wprojT, 1024, 1024);
  transpose_cvt<<<dim3(4096 / 32, 1024 / 32), 256, 0, stream>>>(w_fc1, wfc1T, 1024, 4096);
  transpose_cvt<<<dim3(1024 / 32, 4096 / 32), 256, 0, stream>>>(w_fc2, wfc2T, 4096, 1024);
  rmsnorm_k<<<4096, 256, 0, stream>>>(x, g1, h1);
  gemm_bf16<0><<<dim3(3072 / 128, 4096 / 128), 256, 0, stream>>>(
      h1, wqkvT, b_qkv, nullptr, qkvb, 4096, 3072, 1024);
  qkv_post<<<16384, 256, 0, stream>>>(qkvb, gq, gk, QsB, KsB, VTB);
  attn_fwd<<<dim3(32, 32), 256, 0, stream>>>(QsB, KsB, VTB, gq, gk, Obuf);
  if (S_pr > 1) {
    gemm_bf16<3><<<dim3(1024 / 128, 4096 / 128, S_pr), 256, 0, stream>>>(
        Obuf, wprojT, b_proj, nullptr, proj_part, 4096, 1024, 1024);
    reduce_splitk<<<(MN / 4 + 255) / 256, 256, 0, stream>>>(
        proj_part, S_pr, x, b_proj, x2, 1024, MN);
  } else {
    gemm_bf16<1><<<dim3(1024 / 128, 4096 / 128), 256, 0, stream>>>(
        Obuf, wprojT, b_proj, x, x2, 4096, 1024, 1024);
  }
  rmsnorm_k<<<4096, 256, 0, stream>>>(x2, g2, h2);
  gemm_bf16<2><<<dim3(4096 / 128, 4096 / 128), 256, 0, stream>>>(
      h2, wfc1T, b_fc1, nullptr, h3, 4096, 4096, 1024);
  if (S_fc2 > 1) {
    gemm_bf16<3><<<dim3(1024 / 128, 4096 / 128, S_fc2), 256, 0, stream>>>(
        h3, wfc2T, b_fc2, nullptr, fc2_part, 4096, 1024, 4096);
    reduce_splitk<<<(MN / 4 + 255) / 256, 256, 0, stream>>>(
        fc2_part, S_fc2, x2, b_fc2, out, 1024, MN);
  } else {
    gemm_bf16<1><<<dim3(1024 / 128, 4096 / 128), 256, 0, stream>>>(
        h3, wfc2T, b_fc2, x2, out, 4096, 1024, 4096);
  }
}